// Round 5
// baseline (669.036 us; speedup 1.0000x reference)
//
#include <hip/hip_runtime.h>
#include <stdint.h>
#include <stddef.h>

// ---- problem constants ----
#define BWIN 2048
#define NTOK 49
#define CDIM 384
#define HNUM 12
#define HD   32
#define MTOT (BWIN * NTOK)          // 100352 rows = 784 * 128
#define LOG2E 1.4426950408889634f
// q scale folded with log2(e): logits come out of MFMA in log2 domain
#define QSCALE ((float)(0.17677669529663687 * 1.4426950408889634))

typedef __attribute__((ext_vector_type(8))) short short8;   // 8 bf16 (4 VGPRs)
typedef __attribute__((ext_vector_type(4))) float floatx4;  // MFMA acc

__device__ __forceinline__ unsigned short f2bf(float f) {
    union { float f; unsigned u; } v; v.f = f;
    unsigned u = v.u;
    u = u + 0x7fffu + ((u >> 16) & 1u);   // round-to-nearest-even
    return (unsigned short)(u >> 16);
}

// async global->LDS, 16 B per lane; LDS dest = wave-uniform base + lane*16
__device__ __forceinline__ void gload16(const void* g, void* l) {
    __builtin_amdgcn_global_load_lds(
        (const __attribute__((address_space(1))) void*)g,
        (__attribute__((address_space(3))) void*)l, 16, 0, 0);
}

// =====================================================================
// Kernel 0: fp32 -> bf16 pre-convert (x, qkv_w, proj_w), 2048 elems/block
// =====================================================================
#define XBLK  18816   // 100352*384 / 2048
#define WQBLK 216     // 3*384*384 / 2048
#define WPBLK 72      // 384*384   / 2048
__global__ __launch_bounds__(256) void convert_kernel(
    const float* __restrict__ x, const float* __restrict__ wq,
    const float* __restrict__ wp, unsigned short* __restrict__ xbf,
    unsigned short* __restrict__ wqbf, unsigned short* __restrict__ wpbf)
{
    int bid = blockIdx.x;
    const float* src; unsigned short* dst; size_t base;
    if (bid < XBLK)              { src = x;  dst = xbf;  base = (size_t)bid * 2048; }
    else if (bid < XBLK + WQBLK) { src = wq; dst = wqbf; base = (size_t)(bid - XBLK) * 2048; }
    else                         { src = wp; dst = wpbf; base = (size_t)(bid - XBLK - WQBLK) * 2048; }
    const size_t i = base + (size_t)threadIdx.x * 8;
    float4 a = *(const float4*)(src + i);
    float4 b = *(const float4*)(src + i + 4);
    unsigned short o[8] = {f2bf(a.x), f2bf(a.y), f2bf(a.z), f2bf(a.w),
                           f2bf(b.x), f2bf(b.y), f2bf(b.z), f2bf(b.w)};
    *(uint4*)(dst + i) = *(uint4*)o;
}

// =====================================================================
// Kernel 0b: combined bias table in MFMA accumulator fragment order.
// =====================================================================
__global__ __launch_bounds__(256) void bias_kernel(
    const float* __restrict__ mask, const float* __restrict__ rpb,
    float* __restrict__ cb)
{
    const int bm = blockIdx.x, h = blockIdx.y;
    const int tid = threadIdx.x;
    const int w = tid >> 6, lane = tid & 63;
    const int cg = lane & 15, rg = lane >> 4;
    const int rbase = 16 * w + (rg << 2);
    const float* mk = mask + (size_t)bm * (NTOK * NTOK);
    float o[16];
    #pragma unroll
    for (int j = 0; j < 4; ++j) {
        const int col = 16 * j + cg;
        const bool vc = col < NTOK;
        int yj = 0, xj = 0;
        if (vc) { yj = col / 7; xj = col - yj * 7; }
        #pragma unroll
        for (int r = 0; r < 4; ++r) {
            const int row = rbase + r;
            float v = -1e30f;
            if (vc && row < NTOK) {
                const int yi = row / 7, xi = row - yi * 7;
                const int rel = (yi - yj + 6) * 13 + (xi - xj + 6);
                v = (rpb[rel * HNUM + h] + mk[row * NTOK + col]) * LOG2E;
            }
            o[4 * j + r] = v;
        }
    }
    float* dst = cb + ((size_t)bm * HNUM + h) * 4096 + (size_t)tid * 16;
    #pragma unroll
    for (int j = 0; j < 4; ++j)
        *(float4*)(dst + 4 * j) = *(const float4*)(o + 4 * j);
}

// =====================================================================
// Kernel 1: qkv = xbf @ wqbf^T + qkv_b -> scattered bf16 [3][B][H][N][hd]
// LDS-BW-bound fix: A fragments load global->register directly (no LDS),
// 1-deep reg double buffer. Only B staged in LDS (3 x 8KB, XOR-swizzled,
// counted vmcnt(2) steady state). XCD-chunked block swizzle kept.
// =====================================================================
__global__ __launch_bounds__(256) void qkv_kernel(
    const unsigned short* __restrict__ a, const unsigned short* __restrict__ b,
    const float* __restrict__ bias, unsigned short* __restrict__ outq)
{
    __shared__ __align__(16) unsigned short lB[3][128 * 32];

    const int tid = threadIdx.x;
    const int lane = tid & 63, w = tid >> 6;

    // XCD-chunked swizzle: 7056 blocks, 7056/8 = 882 per XCD (exact)
    const int bid = blockIdx.x;
    const int wg = (bid & 7) * 882 + (bid >> 3);
    const int tN = (wg % 9) * 128;
    const int tM = (wg / 9) * 128;

    // B staging: pre-swizzled source, linear LDS dest (16B/lane)
    const int X = (lane << 4) ^ (((lane >> 3) & 7) << 4);
    const int srow = (w << 5) + (X >> 6);
    const int scol = (X & 63) >> 1;
    const unsigned short* gB = b + (size_t)(tN + srow) * CDIM + scol;

    const int wm = (w & 1) << 6, wn = (w >> 1) << 6;
    const int cg = lane & 15, rg = lane >> 4;

    // A fragment base: row = tM+wm+16i+cg, col = k0 + rg*8 (16B aligned)
    const unsigned short* gAf = a + (size_t)(tM + wm + cg) * CDIM + (rg << 3);

    floatx4 acc[4][4];
    #pragma unroll
    for (int i = 0; i < 4; ++i)
        #pragma unroll
        for (int j = 0; j < 4; ++j) acc[i][j] = (floatx4){0.f, 0.f, 0.f, 0.f};

    // swizzled B fragment byte offsets (within one 8KB buffer)
    int offB[4];
    #pragma unroll
    for (int j = 0; j < 4; ++j) {
        const int rowB = wn + 16 * j + cg;
        const int sB = (rowB << 6) + (rg << 4);
        offB[j] = sB ^ (((sB >> 7) & 7) << 4);
    }

    #define STAGE_B(BUF, K0) do {                                          \
        unsigned short* _lBb = &lB[(BUF)][w << 10];                        \
        gload16(gB + (K0),              _lBb);                             \
        gload16(gB + (K0) + 16 * CDIM,  _lBb + 512);                       \
    } while (0)
    #define LOAD_A(DST, K0) do {                                           \
        DST[0] = *(const short8*)(gAf + (K0));                             \
        DST[1] = *(const short8*)(gAf + 16 * CDIM + (K0));                 \
        DST[2] = *(const short8*)(gAf + 32 * CDIM + (K0));                 \
        DST[3] = *(const short8*)(gAf + 48 * CDIM + (K0));                 \
    } while (0)

    short8 aA0[4], aA1[4];
    STAGE_B(0, 0);       // 2 vm
    LOAD_A(aA0, 0);      // 4 vm
    STAGE_B(1, 32);      // 2 vm  -> 8 outstanding

    #pragma unroll
    for (int t = 0; t < 12; ++t) {
        // in flight (issue order): B[t](2), A[t](4), B[t+1](2).
        // vmcnt(2) drains B[t]+A[t], leaves B[t+1] flying.
        if (t < 11) asm volatile("s_waitcnt vmcnt(2)" ::: "memory");
        else        asm volatile("s_waitcnt vmcnt(0)" ::: "memory");
        __builtin_amdgcn_s_barrier();        // all waves' B[t] landed
        __builtin_amdgcn_sched_barrier(0);   // no ds_read hoists above

        const int bufb = (t % 3) * 8192;
        short8 bfr[4];
        #pragma unroll
        for (int j = 0; j < 4; ++j)
            bfr[j] = *(const short8*)((const char*)lB + bufb + offB[j]);

        if (t < 11) {                        // A[t+1] -> other reg buffer
            if (t & 1) LOAD_A(aA0, (t + 1) * 32);
            else       LOAD_A(aA1, (t + 1) * 32);
        }
        if (t < 10) STAGE_B((t + 2) % 3, (t + 2) * 32);  // buf (t-1)%3: safe

        __builtin_amdgcn_s_setprio(1);
        #pragma unroll
        for (int i = 0; i < 4; ++i)
            #pragma unroll
            for (int j = 0; j < 4; ++j)
                acc[i][j] = __builtin_amdgcn_mfma_f32_16x16x32_bf16(
                    (t & 1) ? aA1[i] : aA0[i], bfr[j], acc[i][j], 0, 0, 0);
        __builtin_amdgcn_s_setprio(0);
    }
    #undef STAGE_B
    #undef LOAD_A

    // epilogue: hoisted index math
    const int r0 = tM + wm + (rg << 2);
    float bv[4], sc[4];
    size_t cjo[4];
    #pragma unroll
    for (int j = 0; j < 4; ++j) {
        const int col = tN + wn + 16 * j + cg;
        bv[j] = bias[col];
        const int which = col / CDIM;
        const int rem = col - which * CDIM;
        const int h = rem >> 5, d = rem & 31;
        sc[j] = (which == 0) ? QSCALE : 1.0f;
        cjo[j] = (size_t)which * (BWIN * HNUM * NTOK * HD)
               + (size_t)h * (NTOK * HD) + d;
    }
    #pragma unroll
    for (int i = 0; i < 4; ++i) {
        #pragma unroll
        for (int r = 0; r < 4; ++r) {
            const int row = r0 + 16 * i + r;
            const int bb = row / NTOK;
            const int n = row - bb * NTOK;
            const size_t ro = (size_t)bb * (HNUM * NTOK * HD) + (size_t)n * HD;
            #pragma unroll
            for (int j = 0; j < 4; ++j)
                outq[cjo[j] + ro] = f2bf((acc[i][j][r] + bv[j]) * sc[j]);
        }
    }
}

// =====================================================================
// Kernel 2: MFMA attention (unchanged)
// =====================================================================
__global__ __launch_bounds__(256) void attn_kernel(
    const unsigned short* __restrict__ qkv, const float* __restrict__ cb,
    unsigned short* __restrict__ outa)
{
    __shared__ __align__(16) unsigned short lq[64][40];
    __shared__ __align__(16) unsigned short lk[64][40];
    __shared__ __align__(16) unsigned short lvt[32][72];
    __shared__ __align__(16) unsigned short lp[64][72];

    const int b = blockIdx.x, h = blockIdx.y;
    const int tid = threadIdx.x;
    const size_t WHICH = (size_t)BWIN * HNUM * NTOK * HD;
    const size_t base = ((size_t)b * HNUM + h) * (NTOK * HD);

    // issue cb fragment loads early (independent of LDS staging)
    const float* cbp = cb + ((size_t)(b & 63) * HNUM + h) * 4096 + (size_t)tid * 16;
    floatx4 z[4];
    #pragma unroll
    for (int j = 0; j < 4; ++j) z[j] = *(const floatx4*)(cbp + 4 * j);

    // phase 0: zero pads, stage Q/K into LDS, V into registers
    for (int e = tid; e < 1152; e += 256)
        ((unsigned*)&lvt[0][0])[e] = 0u;
    if (tid < 240) {
        const int r = 49 + (tid >> 4), c = (tid & 15) * 2;
        *(unsigned*)&lq[r][c] = 0u;
        *(unsigned*)&lk[r][c] = 0u;
    }
    uint4 vreg;
    if (tid < 196) {
        const int n = tid >> 2, d = (tid & 3) * 8;
        *(uint4*)&lq[n][d] = *(const uint4*)(qkv + base + tid * 8);
        *(uint4*)&lk[n][d] = *(const uint4*)(qkv + base + WHICH + tid * 8);
        vreg = *(const uint4*)(qkv + base + 2 * WHICH + tid * 8);
    }
    __syncthreads();

    // phase 1: V transpose write (overlaps QK compute of other waves)
    if (tid < 196) {
        const int n = tid >> 2, d0 = (tid & 3) * 8;
        const unsigned short* vp = (const unsigned short*)&vreg;
        #pragma unroll
        for (int jj = 0; jj < 8; ++jj)
            lvt[d0 + jj][n] = vp[jj];
    }

    const int w = tid >> 6, lane = tid & 63;
    const int cg = lane & 15;
    const int rg = lane >> 4;
    const int rbase = 16 * w + rg * 4;

    short8 aq = *(const short8*)&lq[16 * w + cg][rg * 8];
    floatx4 s[4];
    #pragma unroll
    for (int j = 0; j < 4; ++j) {
        short8 bk = *(const short8*)&lk[16 * j + cg][rg * 8];
        s[j] = __builtin_amdgcn_mfma_f32_16x16x32_bf16(aq, bk, z[j], 0, 0, 0);
    }

    // softmax: logits already in log2 domain, pads are -1e30 -> exp2 = 0
    float l[4] = {0.f, 0.f, 0.f, 0.f};
    #pragma unroll
    for (int j = 0; j < 4; ++j) {
        const int col = 16 * j + cg;
        #pragma unroll
        for (int r = 0; r < 4; ++r) {
            const float e = exp2f(s[j][r]);
            l[r] += e;
            lp[rbase + r][col] = f2bf(e);
        }
    }
    #pragma unroll
    for (int st = 1; st < 16; st <<= 1) {
        #pragma unroll
        for (int r = 0; r < 4; ++r) l[r] += __shfl_xor(l[r], st);
    }
    float linv[4];
    #pragma unroll
    for (int r = 0; r < 4; ++r) linv[r] = 1.f / l[r];
    __syncthreads();

    #pragma unroll
    for (int n = 0; n < 2; ++n) {
        floatx4 o = {0, 0, 0, 0};
        #pragma unroll
        for (int kk = 0; kk < 2; ++kk) {
            short8 ap = *(const short8*)&lp[16 * w + cg][kk * 32 + rg * 8];
            short8 bv = *(const short8*)&lvt[16 * n + cg][kk * 32 + rg * 8];
            o = __builtin_amdgcn_mfma_f32_16x16x32_bf16(ap, bv, o, 0, 0, 0);
        }
        #pragma unroll
        for (int r = 0; r < 4; ++r) {
            const int row = rbase + r;
            if (row < NTOK)
                outa[((size_t)b * NTOK + row) * CDIM + h * HD + n * 16 + cg] =
                    f2bf(o[r] * linv[r]);
        }
    }
}

// =====================================================================
// Kernel 3: out = a @ wpbf^T + proj_b; same A-direct + B-LDS pipeline
// =====================================================================
__global__ __launch_bounds__(256) void proj_kernel(
    const unsigned short* __restrict__ a, const unsigned short* __restrict__ b,
    const float* __restrict__ bias, float* __restrict__ out)
{
    __shared__ __align__(16) unsigned short lB[3][128 * 32];

    const int tid = threadIdx.x;
    const int lane = tid & 63, w = tid >> 6;

    // XCD-chunked swizzle: 2352 blocks, 2352/8 = 294 per XCD (exact)
    const int bid = blockIdx.x;
    const int wg = (bid & 7) * 294 + (bid >> 3);
    const int tN = (wg % 3) * 128;
    const int tM = (wg / 3) * 128;

    const int X = (lane << 4) ^ (((lane >> 3) & 7) << 4);
    const int srow = (w << 5) + (X >> 6);
    const int scol = (X & 63) >> 1;
    const unsigned short* gB = b + (size_t)(tN + srow) * CDIM + scol;

    const int wm = (w & 1) << 6, wn = (w >> 1) << 6;
    const int cg = lane & 15, rg = lane >> 4;

    const unsigned short* gAf = a + (size_t)(tM + wm + cg) * CDIM + (rg << 3);

    floatx4 acc[4][4];
    #pragma unroll
    for (int i = 0; i < 4; ++i)
        #pragma unroll
        for (int j = 0; j < 4; ++j) acc[i][j] = (floatx4){0.f, 0.f, 0.f, 0.f};

    int offB[4];
    #pragma unroll
    for (int j = 0; j < 4; ++j) {
        const int rowB = wn + 16 * j + cg;
        const int sB = (rowB << 6) + (rg << 4);
        offB[j] = sB ^ (((sB >> 7) & 7) << 4);
    }

    #define STAGE_B(BUF, K0) do {                                          \
        unsigned short* _lBb = &lB[(BUF)][w << 10];                        \
        gload16(gB + (K0),              _lBb);                             \
        gload16(gB + (K0) + 16 * CDIM,  _lBb + 512);                       \
    } while (0)
    #define LOAD_A(DST, K0) do {                                           \
        DST[0] = *(const short8*)(gAf + (K0));                             \
        DST[1] = *(const short8*)(gAf + 16 * CDIM + (K0));                 \
        DST[2] = *(const short8*)(gAf + 32 * CDIM + (K0));                 \
        DST[3] = *(const short8*)(gAf + 48 * CDIM + (K0));                 \
    } while (0)

    short8 aA0[4], aA1[4];
    STAGE_B(0, 0);
    LOAD_A(aA0, 0);
    STAGE_B(1, 32);

    #pragma unroll
    for (int t = 0; t < 12; ++t) {
        if (t < 11) asm volatile("s_waitcnt vmcnt(2)" ::: "memory");
        else        asm volatile("s_waitcnt vmcnt(0)" ::: "memory");
        __builtin_amdgcn_s_barrier();
        __builtin_amdgcn_sched_barrier(0);

        const int bufb = (t % 3) * 8192;
        short8 bfr[4];
        #pragma unroll
        for (int j = 0; j < 4; ++j)
            bfr[j] = *(const short8*)((const char*)lB + bufb + offB[j]);

        if (t < 11) {
            if (t & 1) LOAD_A(aA0, (t + 1) * 32);
            else       LOAD_A(aA1, (t + 1) * 32);
        }
        if (t < 10) STAGE_B((t + 2) % 3, (t + 2) * 32);

        __builtin_amdgcn_s_setprio(1);
        #pragma unroll
        for (int i = 0; i < 4; ++i)
            #pragma unroll
            for (int j = 0; j < 4; ++j)
                acc[i][j] = __builtin_amdgcn_mfma_f32_16x16x32_bf16(
                    (t & 1) ? aA1[i] : aA0[i], bfr[j], acc[i][j], 0, 0, 0);
        __builtin_amdgcn_s_setprio(0);
    }
    #undef STAGE_B
    #undef LOAD_A

    const int r0 = tM + wm + (rg << 2);
    #pragma unroll
    for (int j = 0; j < 4; ++j) {
        const int col = tN + wn + 16 * j + cg;
        const float bv = bias[col];
        #pragma unroll
        for (int i = 0; i < 4; ++i) {
            #pragma unroll
            for (int r = 0; r < 4; ++r) {
                const int row = r0 + 16 * i + r;
                out[(size_t)row * CDIM + col] = acc[i][j][r] + bv;
            }
        }
    }
}

// =====================================================================
extern "C" void kernel_launch(void* const* d_in, const int* in_sizes, int n_in,
                              void* d_out, int out_size, void* d_ws, size_t ws_size,
                              hipStream_t stream) {
    const float* x      = (const float*)d_in[0];
    const float* mask   = (const float*)d_in[1];
    const float* qkv_w  = (const float*)d_in[2];
    const float* qkv_b  = (const float*)d_in[3];
    const float* proj_w = (const float*)d_in[4];
    const float* proj_b = (const float*)d_in[5];
    const float* rpb    = (const float*)d_in[6];
    float* out = (float*)d_out;

    unsigned short* ws_qkv  = (unsigned short*)d_ws;                        // 3*B*H*N*hd
    unsigned short* xbf     = ws_qkv + (size_t)3 * BWIN * HNUM * NTOK * HD; // M*C (aliased)
    unsigned short* ws_attn = xbf;   // x_bf16 dead once qkv_kernel completes
    unsigned short* wqbf    = xbf + (size_t)MTOT * CDIM;                    // 3*C*C
    unsigned short* wpbf    = wqbf + (size_t)3 * CDIM * CDIM;               // C*C
    float* cbias            = (float*)(wpbf + (size_t)CDIM * CDIM);        // 64*12*4096 f32

    convert_kernel<<<XBLK + WQBLK + WPBLK, 256, 0, stream>>>(x, qkv_w, proj_w, xbf, wqbf, wpbf);
    bias_kernel<<<dim3(64, HNUM), 256, 0, stream>>>(mask, rpb, cbias);
    qkv_kernel<<<7056, 256, 0, stream>>>(xbf, wqbf, qkv_b, ws_qkv);
    attn_kernel<<<dim3(BWIN, HNUM), 256, 0, stream>>>(ws_qkv, cbias, ws_attn);
    proj_kernel<<<2352, 256, 0, stream>>>(ws_attn, wpbf, proj_b, out);
}

// Round 6
// 622.605 us; speedup vs baseline: 1.0746x; 1.0746x over previous
//
#include <hip/hip_runtime.h>
#include <stdint.h>
#include <stddef.h>

// ---- problem constants ----
#define BWIN 2048
#define NTOK 49
#define CDIM 384
#define HNUM 12
#define HD   32
#define MTOT (BWIN * NTOK)          // 100352 rows = 784 * 128
#define LOG2E 1.4426950408889634f
// q scale folded with log2(e): logits come out of MFMA in log2 domain
#define QSCALE ((float)(0.17677669529663687 * 1.4426950408889634))

typedef __attribute__((ext_vector_type(8))) short short8;   // 8 bf16 (4 VGPRs)
typedef __attribute__((ext_vector_type(4))) float floatx4;  // MFMA acc

__device__ __forceinline__ unsigned short f2bf(float f) {
    union { float f; unsigned u; } v; v.f = f;
    unsigned u = v.u;
    u = u + 0x7fffu + ((u >> 16) & 1u);   // round-to-nearest-even
    return (unsigned short)(u >> 16);
}

// packed f32x2 -> bf16x2, RNE (gfx950 HW instruction; no builtin)
__device__ __forceinline__ unsigned pkbf(float lo, float hi) {
    unsigned r;
    asm volatile("v_cvt_pk_bf16_f32 %0, %1, %2" : "=v"(r) : "v"(lo), "v"(hi));
    return r;
}

// async global->LDS, 16 B per lane; LDS dest = wave-uniform base + lane*16
__device__ __forceinline__ void gload16(const void* g, void* l) {
    __builtin_amdgcn_global_load_lds(
        (const __attribute__((address_space(1))) void*)g,
        (__attribute__((address_space(3))) void*)l, 16, 0, 0);
}

// =====================================================================
// Kernel 0: fp32 -> bf16 pre-convert, WEIGHTS ONLY (qkv_w, proj_w).
// x conversion is folded into qkv_kernel's A-staging.
// =====================================================================
#define WQBLK 216     // 3*384*384 / 2048
#define WPBLK 72      // 384*384   / 2048
__global__ __launch_bounds__(256) void convert_kernel(
    const float* __restrict__ wq, const float* __restrict__ wp,
    unsigned short* __restrict__ wqbf, unsigned short* __restrict__ wpbf)
{
    int bid = blockIdx.x;
    const float* src; unsigned short* dst; size_t base;
    if (bid < WQBLK) { src = wq; dst = wqbf; base = (size_t)bid * 2048; }
    else             { src = wp; dst = wpbf; base = (size_t)(bid - WQBLK) * 2048; }
    const size_t i = base + (size_t)threadIdx.x * 8;
    float4 a = *(const float4*)(src + i);
    float4 b = *(const float4*)(src + i + 4);
    unsigned short o[8] = {f2bf(a.x), f2bf(a.y), f2bf(a.z), f2bf(a.w),
                           f2bf(b.x), f2bf(b.y), f2bf(b.z), f2bf(b.w)};
    *(uint4*)(dst + i) = *(uint4*)o;
}

// =====================================================================
// Kernel 0b: combined bias table in MFMA accumulator fragment order.
// =====================================================================
__global__ __launch_bounds__(256) void bias_kernel(
    const float* __restrict__ mask, const float* __restrict__ rpb,
    float* __restrict__ cb)
{
    const int bm = blockIdx.x, h = blockIdx.y;
    const int tid = threadIdx.x;
    const int w = tid >> 6, lane = tid & 63;
    const int cg = lane & 15, rg = lane >> 4;
    const int rbase = 16 * w + (rg << 2);
    const float* mk = mask + (size_t)bm * (NTOK * NTOK);
    float o[16];
    #pragma unroll
    for (int j = 0; j < 4; ++j) {
        const int col = 16 * j + cg;
        const bool vc = col < NTOK;
        int yj = 0, xj = 0;
        if (vc) { yj = col / 7; xj = col - yj * 7; }
        #pragma unroll
        for (int r = 0; r < 4; ++r) {
            const int row = rbase + r;
            float v = -1e30f;
            if (vc && row < NTOK) {
                const int yi = row / 7, xi = row - yi * 7;
                const int rel = (yi - yj + 6) * 13 + (xi - xj + 6);
                v = (rpb[rel * HNUM + h] + mk[row * NTOK + col]) * LOG2E;
            }
            o[4 * j + r] = v;
        }
    }
    float* dst = cb + ((size_t)bm * HNUM + h) * 4096 + (size_t)tid * 16;
    #pragma unroll
    for (int j = 0; j < 4; ++j)
        *(float4*)(dst + 4 * j) = *(const float4*)(o + 4 * j);
}

// =====================================================================
// Kernel 1: qkv = x @ wqbf^T + qkv_b -> scattered bf16 [3][B][H][N][hd]
// A (x) read as FP32 coalesced -> regs -> cvt_pk -> swizzled ds_write
// (conversion fused; separate x-convert pass eliminated). B via gload_lds.
// r3's counted-vmcnt pipeline: steady vmcnt(2), raw barriers, setprio.
// =====================================================================
__global__ __launch_bounds__(256) void qkv_kernel(
    const float* __restrict__ a, const unsigned short* __restrict__ b,
    const float* __restrict__ bias, unsigned short* __restrict__ outq)
{
    __shared__ __align__(16) unsigned short lA[2][128 * 32];
    __shared__ __align__(16) unsigned short lB[3][128 * 32];

    const int tid = threadIdx.x;
    const int lane = tid & 63, w = tid >> 6;

    // XCD-chunked swizzle: 7056 blocks, 7056/8 = 882 per XCD (exact)
    const int bid = blockIdx.x;
    const int wg = (bid & 7) * 882 + (bid >> 3);
    const int tN = (wg % 9) * 128;
    const int tM = (wg / 9) * 128;

    // B staging: pre-swizzled source, linear LDS dest (16B/lane)
    const int X = (lane << 4) ^ (((lane >> 3) & 7) << 4);
    const int srow = (w << 5) + (X >> 6);
    const int scol = (X & 63) >> 1;
    const unsigned short* gB = b + (size_t)(tN + srow) * CDIM + scol;

    // A staging: each lane reads 16 consecutive f32 of one row (64B),
    // converts to 16 bf16, writes 2x16B to XOR-swizzled LDS offsets.
    const int arow = (w << 5) + (lane >> 1);               // row in 128-tile
    const float* gAx = a + (size_t)(tM + arow) * CDIM + ((lane & 1) << 4);
    const int d0lin = (arow << 6) + ((lane & 1) << 5);     // tile byte addr
    const int dX = ((lane >> 2) & 7) << 4;                 // row bits 1-3
    const int d0 = d0lin ^ dX;
    const int d1 = (d0lin + 16) ^ dX;

    const int wm = (w & 1) << 6, wn = (w >> 1) << 6;
    const int cg = lane & 15, rg = lane >> 4;

    floatx4 acc[4][4];
    #pragma unroll
    for (int i = 0; i < 4; ++i)
        #pragma unroll
        for (int j = 0; j < 4; ++j) acc[i][j] = (floatx4){0.f, 0.f, 0.f, 0.f};

    // swizzled fragment byte offsets (within one 8KB tile)
    int offA[4], offB[4];
    #pragma unroll
    for (int i = 0; i < 4; ++i) {
        const int rowA = wm + 16 * i + cg;
        const int sA = (rowA << 6) + (rg << 4);
        offA[i] = sA ^ (((sA >> 7) & 7) << 4);
        const int rowB = wn + 16 * i + cg;
        const int sB = (rowB << 6) + (rg << 4);
        offB[i] = sB ^ (((sB >> 7) & 7) << 4);
    }

    #define STAGE_B(BUF, K0) do {                                          \
        unsigned short* _lBb = &lB[(BUF)][w << 10];                        \
        gload16(gB + (K0),              _lBb);                             \
        gload16(gB + (K0) + 16 * CDIM,  _lBb + 512);                       \
    } while (0)
    #define ALOAD(SET, K0) do {                                            \
        SET[0] = *(const float4*)(gAx + (K0));                             \
        SET[1] = *(const float4*)(gAx + (K0) + 4);                         \
        SET[2] = *(const float4*)(gAx + (K0) + 8);                         \
        SET[3] = *(const float4*)(gAx + (K0) + 12);                        \
    } while (0)
    #define AWRITE(SET, BUF) do {                                          \
        uint4 q0, q1;                                                      \
        q0.x = pkbf(SET[0].x, SET[0].y); q0.y = pkbf(SET[0].z, SET[0].w);  \
        q0.z = pkbf(SET[1].x, SET[1].y); q0.w = pkbf(SET[1].z, SET[1].w);  \
        q1.x = pkbf(SET[2].x, SET[2].y); q1.y = pkbf(SET[2].z, SET[2].w);  \
        q1.z = pkbf(SET[3].x, SET[3].y); q1.w = pkbf(SET[3].z, SET[3].w);  \
        *(uint4*)((char*)&lA[(BUF)][0] + d0) = q0;                         \
        *(uint4*)((char*)&lA[(BUF)][0] + d1) = q1;                         \
    } while (0)

    float4 rA0[4], rA1[4];
    ALOAD(rA0, 0);        // A[0]: 4 vm
    STAGE_B(0, 0);        // B[0]: 2 vm
    ALOAD(rA1, 32);       // A[1]: 4 vm
    STAGE_B(1, 32);       // B[1]: 2 vm
    asm volatile("s_waitcnt vmcnt(8)" ::: "memory");   // A[0] regs arrived
    AWRITE(rA0, 0);

    #pragma unroll
    for (int t = 0; t < 12; ++t) {
        // steady state outstanding: B[t](2, oldest), A[t+1](4), B[t+1](2).
        // vmcnt(2) drains B[t] (needed now) + A[t+1] (written this iter),
        // leaves B[t+1] flying. Never 0 until the last tile.
        if (t < 11) asm volatile("s_waitcnt vmcnt(2)" ::: "memory");
        else        asm volatile("s_waitcnt vmcnt(0)" ::: "memory");
        asm volatile("s_waitcnt lgkmcnt(0)" ::: "memory");  // ds_write visible
        __builtin_amdgcn_s_barrier();
        __builtin_amdgcn_sched_barrier(0);

        short8 af[4], bfr[4];
        #pragma unroll
        for (int i = 0; i < 4; ++i)
            af[i] = *(const short8*)((const char*)&lA[t & 1][0] + offA[i]);
        #pragma unroll
        for (int j = 0; j < 4; ++j)
            bfr[j] = *(const short8*)((const char*)&lB[t % 3][0] + offB[j]);

        if (t <= 9) {                       // A[t+2] -> set (t+2)&1 = t&1
            if (t & 1) ALOAD(rA1, (t + 2) * 32);
            else       ALOAD(rA0, (t + 2) * 32);
        }
        if (t <= 10) {                      // write A[t+1] (buf (t+1)&1)
            if (t & 1) AWRITE(rA0, (t + 1) & 1);
            else       AWRITE(rA1, (t + 1) & 1);
        }
        if (t <= 9) STAGE_B((t + 2) % 3, (t + 2) * 32);   // buf (t-1)%3: safe

        __builtin_amdgcn_s_setprio(1);
        #pragma unroll
        for (int i = 0; i < 4; ++i)
            #pragma unroll
            for (int j = 0; j < 4; ++j)
                acc[i][j] = __builtin_amdgcn_mfma_f32_16x16x32_bf16(af[i], bfr[j], acc[i][j], 0, 0, 0);
        __builtin_amdgcn_s_setprio(0);
    }
    #undef STAGE_B
    #undef ALOAD
    #undef AWRITE

    // epilogue: hoisted index math
    const int r0 = tM + wm + (rg << 2);
    float bv[4], sc[4];
    size_t cjo[4];
    #pragma unroll
    for (int j = 0; j < 4; ++j) {
        const int col = tN + wn + 16 * j + cg;
        bv[j] = bias[col];
        const int which = col / CDIM;
        const int rem = col - which * CDIM;
        const int h = rem >> 5, d = rem & 31;
        sc[j] = (which == 0) ? QSCALE : 1.0f;
        cjo[j] = (size_t)which * (BWIN * HNUM * NTOK * HD)
               + (size_t)h * (NTOK * HD) + d;
    }
    #pragma unroll
    for (int i = 0; i < 4; ++i) {
        #pragma unroll
        for (int r = 0; r < 4; ++r) {
            const int row = r0 + 16 * i + r;
            const int bb = row / NTOK;
            const int n = row - bb * NTOK;
            const size_t ro = (size_t)bb * (HNUM * NTOK * HD) + (size_t)n * HD;
            #pragma unroll
            for (int j = 0; j < 4; ++j)
                outq[cjo[j] + ro] = f2bf((acc[i][j][r] + bv[j]) * sc[j]);
        }
    }
}

// =====================================================================
// Kernel 2: MFMA attention (unchanged)
// =====================================================================
__global__ __launch_bounds__(256) void attn_kernel(
    const unsigned short* __restrict__ qkv, const float* __restrict__ cb,
    unsigned short* __restrict__ outa)
{
    __shared__ __align__(16) unsigned short lq[64][40];
    __shared__ __align__(16) unsigned short lk[64][40];
    __shared__ __align__(16) unsigned short lvt[32][72];
    __shared__ __align__(16) unsigned short lp[64][72];

    const int b = blockIdx.x, h = blockIdx.y;
    const int tid = threadIdx.x;
    const size_t WHICH = (size_t)BWIN * HNUM * NTOK * HD;
    const size_t base = ((size_t)b * HNUM + h) * (NTOK * HD);

    // issue cb fragment loads early (independent of LDS staging)
    const float* cbp = cb + ((size_t)(b & 63) * HNUM + h) * 4096 + (size_t)tid * 16;
    floatx4 z[4];
    #pragma unroll
    for (int j = 0; j < 4; ++j) z[j] = *(const floatx4*)(cbp + 4 * j);

    // phase 0: zero pads, stage Q/K into LDS, V into registers
    for (int e = tid; e < 1152; e += 256)
        ((unsigned*)&lvt[0][0])[e] = 0u;
    if (tid < 240) {
        const int r = 49 + (tid >> 4), c = (tid & 15) * 2;
        *(unsigned*)&lq[r][c] = 0u;
        *(unsigned*)&lk[r][c] = 0u;
    }
    uint4 vreg;
    if (tid < 196) {
        const int n = tid >> 2, d = (tid & 3) * 8;
        *(uint4*)&lq[n][d] = *(const uint4*)(qkv + base + tid * 8);
        *(uint4*)&lk[n][d] = *(const uint4*)(qkv + base + WHICH + tid * 8);
        vreg = *(const uint4*)(qkv + base + 2 * WHICH + tid * 8);
    }
    __syncthreads();

    // phase 1: V transpose write (overlaps QK compute of other waves)
    if (tid < 196) {
        const int n = tid >> 2, d0 = (tid & 3) * 8;
        const unsigned short* vp = (const unsigned short*)&vreg;
        #pragma unroll
        for (int jj = 0; jj < 8; ++jj)
            lvt[d0 + jj][n] = vp[jj];
    }

    const int w = tid >> 6, lane = tid & 63;
    const int cg = lane & 15;
    const int rg = lane >> 4;
    const int rbase = 16 * w + rg * 4;

    short8 aq = *(const short8*)&lq[16 * w + cg][rg * 8];
    floatx4 s[4];
    #pragma unroll
    for (int j = 0; j < 4; ++j) {
        short8 bk = *(const short8*)&lk[16 * j + cg][rg * 8];
        s[j] = __builtin_amdgcn_mfma_f32_16x16x32_bf16(aq, bk, z[j], 0, 0, 0);
    }

    // softmax: logits already in log2 domain, pads are -1e30 -> exp2 = 0
    float l[4] = {0.f, 0.f, 0.f, 0.f};
    #pragma unroll
    for (int j = 0; j < 4; ++j) {
        const int col = 16 * j + cg;
        #pragma unroll
        for (int r = 0; r < 4; ++r) {
            const float e = exp2f(s[j][r]);
            l[r] += e;
            lp[rbase + r][col] = f2bf(e);
        }
    }
    #pragma unroll
    for (int st = 1; st < 16; st <<= 1) {
        #pragma unroll
        for (int r = 0; r < 4; ++r) l[r] += __shfl_xor(l[r], st);
    }
    float linv[4];
    #pragma unroll
    for (int r = 0; r < 4; ++r) linv[r] = 1.f / l[r];
    __syncthreads();

    #pragma unroll
    for (int n = 0; n < 2; ++n) {
        floatx4 o = {0, 0, 0, 0};
        #pragma unroll
        for (int kk = 0; kk < 2; ++kk) {
            short8 ap = *(const short8*)&lp[16 * w + cg][kk * 32 + rg * 8];
            short8 bv = *(const short8*)&lvt[16 * n + cg][kk * 32 + rg * 8];
            o = __builtin_amdgcn_mfma_f32_16x16x32_bf16(ap, bv, o, 0, 0, 0);
        }
        #pragma unroll
        for (int r = 0; r < 4; ++r) {
            const int row = rbase + r;
            if (row < NTOK)
                outa[((size_t)b * NTOK + row) * CDIM + h * HD + n * 16 + cg] =
                    f2bf(o[r] * linv[r]);
        }
    }
}

// =====================================================================
// Kernel 3: out = a @ wpbf^T + proj_b; r3 counted-vmcnt pipeline
// =====================================================================
__global__ __launch_bounds__(256) void proj_kernel(
    const unsigned short* __restrict__ a, const unsigned short* __restrict__ b,
    const float* __restrict__ bias, float* __restrict__ out)
{
    __shared__ __align__(16) unsigned short lA[3][128 * 32];
    __shared__ __align__(16) unsigned short lB[3][128 * 32];

    const int tid = threadIdx.x;
    const int lane = tid & 63, w = tid >> 6;

    // XCD-chunked swizzle: 2352 blocks, 2352/8 = 294 per XCD (exact)
    const int bid = blockIdx.x;
    const int wg = (bid & 7) * 294 + (bid >> 3);
    const int tN = (wg % 3) * 128;
    const int tM = (wg / 3) * 128;

    const int X = (lane << 4) ^ (((lane >> 3) & 7) << 4);
    const int srow = (w << 5) + (X >> 6);
    const int scol = (X & 63) >> 1;
    const unsigned short* gA = a + (size_t)(tM + srow) * CDIM + scol;
    const unsigned short* gB = b + (size_t)(tN + srow) * CDIM + scol;

    const int wm = (w & 1) << 6, wn = (w >> 1) << 6;
    const int cg = lane & 15, rg = lane >> 4;

    floatx4 acc[4][4];
    #pragma unroll
    for (int i = 0; i < 4; ++i)
        #pragma unroll
        for (int j = 0; j < 4; ++j) acc[i][j] = (floatx4){0.f, 0.f, 0.f, 0.f};

    int offA[4], offB[4];
    #pragma unroll
    for (int i = 0; i < 4; ++i) {
        const int rowA = wm + 16 * i + cg;
        const int sA = (rowA << 6) + (rg << 4);
        offA[i] = sA ^ (((sA >> 7) & 7) << 4);
        const int rowB = wn + 16 * i + cg;
        const int sB = (rowB << 6) + (rg << 4);
        offB[i] = sB ^ (((sB >> 7) & 7) << 4);
    }

    #define STAGE_P(BUF, K0) do {                                          \
        unsigned short* _lAb = &lA[(BUF)][w << 10];                        \
        unsigned short* _lBb = &lB[(BUF)][w << 10];                        \
        gload16(gA + (K0),              _lAb);                             \
        gload16(gA + (K0) + 16 * CDIM,  _lAb + 512);                       \
        gload16(gB + (K0),              _lBb);                             \
        gload16(gB + (K0) + 16 * CDIM,  _lBb + 512);                       \
    } while (0)

    STAGE_P(0, 0);
    STAGE_P(1, 32);

    #pragma unroll
    for (int t = 0; t < 12; ++t) {
        if (t < 11) asm volatile("s_waitcnt vmcnt(4)" ::: "memory");
        else        asm volatile("s_waitcnt vmcnt(0)" ::: "memory");
        __builtin_amdgcn_s_barrier();
        __builtin_amdgcn_sched_barrier(0);

        const int bufb = (t % 3) * 8192;
        short8 af[4], bfr[4];
        #pragma unroll
        for (int i = 0; i < 4; ++i)
            af[i] = *(const short8*)((const char*)lA + bufb + offA[i]);
        #pragma unroll
        for (int j = 0; j < 4; ++j)
            bfr[j] = *(const short8*)((const char*)lB + bufb + offB[j]);

        if (t < 10) STAGE_P((t + 2) % 3, (t + 2) * 32);

        __builtin_amdgcn_s_setprio(1);
        #pragma unroll
        for (int i = 0; i < 4; ++i)
            #pragma unroll
            for (int j = 0; j < 4; ++j)
                acc[i][j] = __builtin_amdgcn_mfma_f32_16x16x32_bf16(af[i], bfr[j], acc[i][j], 0, 0, 0);
        __builtin_amdgcn_s_setprio(0);
    }
    #undef STAGE_P

    const int r0 = tM + wm + (rg << 2);
    #pragma unroll
    for (int j = 0; j < 4; ++j) {
        const int col = tN + wn + 16 * j + cg;
        const float bv = bias[col];
        #pragma unroll
        for (int i = 0; i < 4; ++i) {
            #pragma unroll
            for (int r = 0; r < 4; ++r) {
                const int row = r0 + 16 * i + r;
                out[(size_t)row * CDIM + col] = acc[i][j][r] + bv;
            }
        }
    }
}

// =====================================================================
extern "C" void kernel_launch(void* const* d_in, const int* in_sizes, int n_in,
                              void* d_out, int out_size, void* d_ws, size_t ws_size,
                              hipStream_t stream) {
    const float* x      = (const float*)d_in[0];
    const float* mask   = (const float*)d_in[1];
    const float* qkv_w  = (const float*)d_in[2];
    const float* qkv_b  = (const float*)d_in[3];
    const float* proj_w = (const float*)d_in[4];
    const float* proj_b = (const float*)d_in[5];
    const float* rpb    = (const float*)d_in[6];
    float* out = (float*)d_out;

    unsigned short* ws_qkv  = (unsigned short*)d_ws;                        // 3*B*H*N*hd
    unsigned short* ws_attn = ws_qkv + (size_t)3 * BWIN * HNUM * NTOK * HD; // M*C bf16
    unsigned short* wqbf    = ws_attn + (size_t)MTOT * CDIM;                // 3*C*C
    unsigned short* wpbf    = wqbf + (size_t)3 * CDIM * CDIM;               // C*C
    float* cbias            = (float*)(wpbf + (size_t)CDIM * CDIM);        // 64*12*4096 f32

    convert_kernel<<<WQBLK + WPBLK, 256, 0, stream>>>(qkv_w, proj_w, wqbf, wpbf);
    bias_kernel<<<dim3(64, HNUM), 256, 0, stream>>>(mask, rpb, cbias);
    qkv_kernel<<<7056, 256, 0, stream>>>(x, wqbf, qkv_b, ws_qkv);
    attn_kernel<<<dim3(BWIN, HNUM), 256, 0, stream>>>(ws_qkv, cbias, ws_attn);
    proj_kernel<<<2352, 256, 0, stream>>>(ws_attn, wpbf, proj_b, out);
}

// Round 7
// 588.471 us; speedup vs baseline: 1.1369x; 1.0580x over previous
//
#include <hip/hip_runtime.h>
#include <stdint.h>
#include <stddef.h>

// ---- problem constants ----
#define BWIN 2048
#define NTOK 49
#define CDIM 384
#define HNUM 12
#define HD   32
#define MTOT (BWIN * NTOK)          // 100352 rows = 784 * 128
#define LOG2E 1.4426950408889634f
// q scale folded with log2(e): logits come out of MFMA in log2 domain
#define QSCALE ((float)(0.17677669529663687 * 1.4426950408889634))

typedef __attribute__((ext_vector_type(8))) short short8;   // 8 bf16 (4 VGPRs)
typedef __attribute__((ext_vector_type(4))) float floatx4;  // MFMA acc

__device__ __forceinline__ unsigned short f2bf(float f) {
    union { float f; unsigned u; } v; v.f = f;
    unsigned u = v.u;
    u = u + 0x7fffu + ((u >> 16) & 1u);   // round-to-nearest-even
    return (unsigned short)(u >> 16);
}

// async global->LDS, 16 B per lane; LDS dest = wave-uniform base + lane*16
__device__ __forceinline__ void gload16(const void* g, void* l) {
    __builtin_amdgcn_global_load_lds(
        (const __attribute__((address_space(1))) void*)g,
        (__attribute__((address_space(3))) void*)l, 16, 0, 0);
}

// =====================================================================
// Kernel 0: fp32 -> bf16 pre-convert (x, qkv_w, proj_w), 2048 elems/block
// =====================================================================
#define XBLK  18816   // 100352*384 / 2048
#define WQBLK 216     // 3*384*384 / 2048
#define WPBLK 72      // 384*384   / 2048
__global__ __launch_bounds__(256) void convert_kernel(
    const float* __restrict__ x, const float* __restrict__ wq,
    const float* __restrict__ wp, unsigned short* __restrict__ xbf,
    unsigned short* __restrict__ wqbf, unsigned short* __restrict__ wpbf)
{
    int bid = blockIdx.x;
    const float* src; unsigned short* dst; size_t base;
    if (bid < XBLK)              { src = x;  dst = xbf;  base = (size_t)bid * 2048; }
    else if (bid < XBLK + WQBLK) { src = wq; dst = wqbf; base = (size_t)(bid - XBLK) * 2048; }
    else                         { src = wp; dst = wpbf; base = (size_t)(bid - XBLK - WQBLK) * 2048; }
    const size_t i = base + (size_t)threadIdx.x * 8;
    float4 a = *(const float4*)(src + i);
    float4 b = *(const float4*)(src + i + 4);
    unsigned short o[8] = {f2bf(a.x), f2bf(a.y), f2bf(a.z), f2bf(a.w),
                           f2bf(b.x), f2bf(b.y), f2bf(b.z), f2bf(b.w)};
    *(uint4*)(dst + i) = *(uint4*)o;
}

// =====================================================================
// Kernel 0b: combined bias table in MFMA accumulator fragment order.
//   cb[bm][h][tid][j*4+r] = (rpb[rel(row,col)] + mask[bm][row][col]) * LOG2E
//   out-of-range slots = -1e30 (exp2 -> 0, so no predicates in attn)
// =====================================================================
__global__ __launch_bounds__(256) void bias_kernel(
    const float* __restrict__ mask, const float* __restrict__ rpb,
    float* __restrict__ cb)
{
    const int bm = blockIdx.x, h = blockIdx.y;
    const int tid = threadIdx.x;
    const int w = tid >> 6, lane = tid & 63;
    const int cg = lane & 15, rg = lane >> 4;
    const int rbase = 16 * w + (rg << 2);
    const float* mk = mask + (size_t)bm * (NTOK * NTOK);
    float o[16];
    #pragma unroll
    for (int j = 0; j < 4; ++j) {
        const int col = 16 * j + cg;
        const bool vc = col < NTOK;
        int yj = 0, xj = 0;
        if (vc) { yj = col / 7; xj = col - yj * 7; }
        #pragma unroll
        for (int r = 0; r < 4; ++r) {
            const int row = rbase + r;
            float v = -1e30f;
            if (vc && row < NTOK) {
                const int yi = row / 7, xi = row - yi * 7;
                const int rel = (yi - yj + 6) * 13 + (xi - xj + 6);
                v = (rpb[rel * HNUM + h] + mk[row * NTOK + col]) * LOG2E;
            }
            o[4 * j + r] = v;
        }
    }
    float* dst = cb + ((size_t)bm * HNUM + h) * 4096 + (size_t)tid * 16;
    #pragma unroll
    for (int j = 0; j < 4; ++j)
        *(float4*)(dst + 4 * j) = *(const float4*)(o + 4 * j);
}

// =====================================================================
// Kernel 1: qkv = xbf @ wqbf^T + qkv_b -> scattered bf16 [3][B][H][N][hd]
// r3 verified-best: XCD-chunked swizzle + LDS XOR swizzle + 3-buffer
// counted-vmcnt pipeline (steady vmcnt(4), raw barriers, setprio).
// =====================================================================
__global__ __launch_bounds__(256) void qkv_kernel(
    const unsigned short* __restrict__ a, const unsigned short* __restrict__ b,
    const float* __restrict__ bias, unsigned short* __restrict__ outq)
{
    __shared__ __align__(16) unsigned short lA[3][128 * 32];
    __shared__ __align__(16) unsigned short lB[3][128 * 32];

    const int tid = threadIdx.x;
    const int lane = tid & 63, w = tid >> 6;

    // XCD-chunked swizzle: 7056 blocks, 7056/8 = 882 per XCD (exact)
    const int bid = blockIdx.x;
    const int wg = (bid & 7) * 882 + (bid >> 3);
    const int tN = (wg % 9) * 128;
    const int tM = (wg / 9) * 128;

    const int X = (lane << 4) ^ (((lane >> 3) & 7) << 4);
    const int srow = (w << 5) + (X >> 6);
    const int scol = (X & 63) >> 1;
    const unsigned short* gA = a + (size_t)(tM + srow) * CDIM + scol;
    const unsigned short* gB = b + (size_t)(tN + srow) * CDIM + scol;

    const int wm = (w & 1) << 6, wn = (w >> 1) << 6;
    const int cg = lane & 15, rg = lane >> 4;

    floatx4 acc[4][4];
    #pragma unroll
    for (int i = 0; i < 4; ++i)
        #pragma unroll
        for (int j = 0; j < 4; ++j) acc[i][j] = (floatx4){0.f, 0.f, 0.f, 0.f};

    int offA[4], offB[4];
    #pragma unroll
    for (int i = 0; i < 4; ++i) {
        const int rowA = wm + 16 * i + cg;
        const int sA = (rowA << 6) + (rg << 4);
        offA[i] = sA ^ (((sA >> 7) & 7) << 4);
        const int rowB = wn + 16 * i + cg;
        const int sB = (rowB << 6) + (rg << 4);
        offB[i] = sB ^ (((sB >> 7) & 7) << 4);
    }

    #define STAGE_Q(BUF, K0) do {                                          \
        unsigned short* _lAb = &lA[(BUF)][w << 10];                        \
        unsigned short* _lBb = &lB[(BUF)][w << 10];                        \
        gload16(gA + (K0),              _lAb);                             \
        gload16(gA + (K0) + 16 * CDIM,  _lAb + 512);                       \
        gload16(gB + (K0),              _lBb);                             \
        gload16(gB + (K0) + 16 * CDIM,  _lBb + 512);                       \
    } while (0)

    STAGE_Q(0, 0);
    STAGE_Q(1, 32);

    #pragma unroll
    for (int t = 0; t < 12; ++t) {
        if (t < 11) asm volatile("s_waitcnt vmcnt(4)" ::: "memory");
        else        asm volatile("s_waitcnt vmcnt(0)" ::: "memory");
        __builtin_amdgcn_s_barrier();
        __builtin_amdgcn_sched_barrier(0);

        const int bufb = (t % 3) * 8192;
        short8 af[4], bfr[4];
        #pragma unroll
        for (int i = 0; i < 4; ++i)
            af[i] = *(const short8*)((const char*)lA + bufb + offA[i]);
        #pragma unroll
        for (int j = 0; j < 4; ++j)
            bfr[j] = *(const short8*)((const char*)lB + bufb + offB[j]);

        if (t < 10) STAGE_Q((t + 2) % 3, (t + 2) * 32);

        __builtin_amdgcn_s_setprio(1);
        #pragma unroll
        for (int i = 0; i < 4; ++i)
            #pragma unroll
            for (int j = 0; j < 4; ++j)
                acc[i][j] = __builtin_amdgcn_mfma_f32_16x16x32_bf16(af[i], bfr[j], acc[i][j], 0, 0, 0);
        __builtin_amdgcn_s_setprio(0);
    }
    #undef STAGE_Q

    const int r0 = tM + wm + (rg << 2);
    float bv[4], sc[4];
    size_t cjo[4];
    #pragma unroll
    for (int j = 0; j < 4; ++j) {
        const int col = tN + wn + 16 * j + cg;
        bv[j] = bias[col];
        const int which = col / CDIM;
        const int rem = col - which * CDIM;
        const int h = rem >> 5, d = rem & 31;
        sc[j] = (which == 0) ? QSCALE : 1.0f;
        cjo[j] = (size_t)which * (BWIN * HNUM * NTOK * HD)
               + (size_t)h * (NTOK * HD) + d;
    }
    #pragma unroll
    for (int i = 0; i < 4; ++i) {
        #pragma unroll
        for (int r = 0; r < 4; ++r) {
            const int row = r0 + 16 * i + r;
            const int bb = row / NTOK;
            const int n = row - bb * NTOK;
            const size_t ro = (size_t)bb * (HNUM * NTOK * HD) + (size_t)n * HD;
            #pragma unroll
            for (int j = 0; j < 4; ++j)
                outq[cjo[j] + ro] = f2bf((acc[i][j][r] + bv[j]) * sc[j]);
        }
    }
}

// =====================================================================
// Kernel 2: MFMA attention — one block per window b, loops all 12 heads.
// Head h+1's q/k/v/cb prefetched into registers during head h's compute;
// LDS tiles single-buffered (24 KB -> 6 blocks/CU); raw barriers with
// lgkmcnt-only drains so prefetch loads stay in flight across softmax+PV.
// =====================================================================
__global__ __launch_bounds__(256) void attn_kernel(
    const unsigned short* __restrict__ qkv, const float* __restrict__ cb,
    unsigned short* __restrict__ outa)
{
    __shared__ __align__(16) unsigned short lq[64][40];
    __shared__ __align__(16) unsigned short lk[64][40];
    __shared__ __align__(16) unsigned short lvt[32][72];
    __shared__ __align__(16) unsigned short lp[64][72];

    const int b = blockIdx.x;
    const int tid = threadIdx.x;
    const size_t WHICH = (size_t)BWIN * HNUM * NTOK * HD;
    const size_t hstep = (size_t)NTOK * HD;
    const size_t base0 = (size_t)b * HNUM * hstep;

    const float* cbb = cb + (size_t)(b & 63) * HNUM * 4096 + (size_t)tid * 16;

    // zero pads ONCE: data writes below only touch rows/cols < 49 regions
    for (int e = tid; e < 1152; e += 256)
        ((unsigned*)&lvt[0][0])[e] = 0u;
    if (tid < 240) {
        const int r = 49 + (tid >> 4), c = (tid & 15) * 2;
        *(unsigned*)&lq[r][c] = 0u;
        *(unsigned*)&lk[r][c] = 0u;
    }

    const int w = tid >> 6, lane = tid & 63;
    const int cg = lane & 15, rg = lane >> 4;
    const int rbase = 16 * w + (rg << 2);
    const int vn = tid >> 2, vd = (tid & 3) * 8;

    // prologue: head 0
    uint4 vq, vk, vv;
    if (tid < 196) {
        vq = *(const uint4*)(qkv + base0 + tid * 8);
        vk = *(const uint4*)(qkv + base0 + WHICH + tid * 8);
        vv = *(const uint4*)(qkv + base0 + 2 * WHICH + tid * 8);
    }
    floatx4 z[4];
    #pragma unroll
    for (int j = 0; j < 4; ++j) z[j] = *(const floatx4*)(cbb + 4 * j);
    if (tid < 196) {
        *(uint4*)&lq[vn][vd] = vq;
        *(uint4*)&lk[vn][vd] = vk;
        const unsigned short* vp = (const unsigned short*)&vv;
        #pragma unroll
        for (int jj = 0; jj < 8; ++jj)
            lvt[vd + jj][vn] = vp[jj];
    }
    __syncthreads();

    for (int h = 0; h < HNUM; ++h) {
        // --- QK^T (+bias via accumulator init) ---
        short8 aq = *(const short8*)&lq[16 * w + cg][rg * 8];
        floatx4 s[4];
        #pragma unroll
        for (int j = 0; j < 4; ++j) {
            short8 bk = *(const short8*)&lk[16 * j + cg][rg * 8];
            s[j] = __builtin_amdgcn_mfma_f32_16x16x32_bf16(aq, bk, z[j], 0, 0, 0);
        }

        // --- prefetch head h+1 into registers (latency hidden by SM+PV) ---
        floatx4 zn[4];
        if (h < HNUM - 1) {
            const size_t baseh = base0 + (size_t)(h + 1) * hstep;
            if (tid < 196) {
                vq = *(const uint4*)(qkv + baseh + tid * 8);
                vk = *(const uint4*)(qkv + baseh + WHICH + tid * 8);
                vv = *(const uint4*)(qkv + baseh + 2 * WHICH + tid * 8);
            }
            const float* cbn = cbb + (size_t)(h + 1) * 4096;
            #pragma unroll
            for (int j = 0; j < 4; ++j) zn[j] = *(const floatx4*)(cbn + 4 * j);
        }

        // --- softmax (log2 domain, no max-sub; pads -1e30 -> 0) ---
        float l[4] = {0.f, 0.f, 0.f, 0.f};
        #pragma unroll
        for (int j = 0; j < 4; ++j) {
            const int col = 16 * j + cg;
            #pragma unroll
            for (int r = 0; r < 4; ++r) {
                const float e = exp2f(s[j][r]);
                l[r] += e;
                lp[rbase + r][col] = f2bf(e);
            }
        }
        #pragma unroll
        for (int st = 1; st < 16; st <<= 1) {
            #pragma unroll
            for (int r = 0; r < 4; ++r) l[r] += __shfl_xor(l[r], st);
        }
        float linv[4];
        #pragma unroll
        for (int r = 0; r < 4; ++r) linv[r] = 1.f / l[r];

        // mid barrier: lp writes visible; NO vmcnt drain (prefetch flies on)
        asm volatile("s_waitcnt lgkmcnt(0)" ::: "memory");
        __builtin_amdgcn_s_barrier();
        __builtin_amdgcn_sched_barrier(0);

        // --- PV + output store ---
        #pragma unroll
        for (int n = 0; n < 2; ++n) {
            floatx4 o = {0, 0, 0, 0};
            #pragma unroll
            for (int kk = 0; kk < 2; ++kk) {
                short8 ap = *(const short8*)&lp[16 * w + cg][kk * 32 + rg * 8];
                short8 bvv = *(const short8*)&lvt[16 * n + cg][kk * 32 + rg * 8];
                o = __builtin_amdgcn_mfma_f32_16x16x32_bf16(ap, bvv, o, 0, 0, 0);
            }
            #pragma unroll
            for (int r = 0; r < 4; ++r) {
                const int row = rbase + r;
                if (row < NTOK)
                    outa[((size_t)b * NTOK + row) * CDIM + h * HD + n * 16 + cg] =
                        f2bf(o[r] * linv[r]);
            }
        }

        // end barrier: all lvt/lp reads landed in regs; buffers now writable
        __builtin_amdgcn_s_barrier();
        __builtin_amdgcn_sched_barrier(0);

        if (h < HNUM - 1) {
            if (tid < 196) {             // compiler inserts vmcnt waits here
                *(uint4*)&lq[vn][vd] = vq;
                *(uint4*)&lk[vn][vd] = vk;
                const unsigned short* vp = (const unsigned short*)&vv;
                #pragma unroll
                for (int jj = 0; jj < 8; ++jj)
                    lvt[vd + jj][vn] = vp[jj];
            }
            #pragma unroll
            for (int j = 0; j < 4; ++j) z[j] = zn[j];
            // entry barrier for next head: writes visible
            asm volatile("s_waitcnt lgkmcnt(0)" ::: "memory");
            __builtin_amdgcn_s_barrier();
            __builtin_amdgcn_sched_barrier(0);
        }
    }
}

// =====================================================================
// Kernel 3: out = a @ wpbf^T + proj_b; r3 counted-vmcnt pipeline
// =====================================================================
__global__ __launch_bounds__(256) void proj_kernel(
    const unsigned short* __restrict__ a, const unsigned short* __restrict__ b,
    const float* __restrict__ bias, float* __restrict__ out)
{
    __shared__ __align__(16) unsigned short lA[3][128 * 32];
    __shared__ __align__(16) unsigned short lB[3][128 * 32];

    const int tid = threadIdx.x;
    const int lane = tid & 63, w = tid >> 6;

    const int bid = blockIdx.x;
    const int wg = (bid & 7) * 294 + (bid >> 3);
    const int tN = (wg % 3) * 128;
    const int tM = (wg / 3) * 128;

    const int X = (lane << 4) ^ (((lane >> 3) & 7) << 4);
    const int srow = (w << 5) + (X >> 6);
    const int scol = (X & 63) >> 1;
    const unsigned short* gA = a + (size_t)(tM + srow) * CDIM + scol;
    const unsigned short* gB = b + (size_t)(tN + srow) * CDIM + scol;

    const int wm = (w & 1) << 6, wn = (w >> 1) << 6;
    const int cg = lane & 15, rg = lane >> 4;

    floatx4 acc[4][4];
    #pragma unroll
    for (int i = 0; i < 4; ++i)
        #pragma unroll
        for (int j = 0; j < 4; ++j) acc[i][j] = (floatx4){0.f, 0.f, 0.f, 0.f};

    int offA[4], offB[4];
    #pragma unroll
    for (int i = 0; i < 4; ++i) {
        const int rowA = wm + 16 * i + cg;
        const int sA = (rowA << 6) + (rg << 4);
        offA[i] = sA ^ (((sA >> 7) & 7) << 4);
        const int rowB = wn + 16 * i + cg;
        const int sB = (rowB << 6) + (rg << 4);
        offB[i] = sB ^ (((sB >> 7) & 7) << 4);
    }

    #define STAGE_P(BUF, K0) do {                                          \
        unsigned short* _lAb = &lA[(BUF)][w << 10];                        \
        unsigned short* _lBb = &lB[(BUF)][w << 10];                        \
        gload16(gA + (K0),              _lAb);                             \
        gload16(gA + (K0) + 16 * CDIM,  _lAb + 512);                       \
        gload16(gB + (K0),              _lBb);                             \
        gload16(gB + (K0) + 16 * CDIM,  _lBb + 512);                       \
    } while (0)

    STAGE_P(0, 0);
    STAGE_P(1, 32);

    #pragma unroll
    for (int t = 0; t < 12; ++t) {
        if (t < 11) asm volatile("s_waitcnt vmcnt(4)" ::: "memory");
        else        asm volatile("s_waitcnt vmcnt(0)" ::: "memory");
        __builtin_amdgcn_s_barrier();
        __builtin_amdgcn_sched_barrier(0);

        const int bufb = (t % 3) * 8192;
        short8 af[4], bfr[4];
        #pragma unroll
        for (int i = 0; i < 4; ++i)
            af[i] = *(const short8*)((const char*)lA + bufb + offA[i]);
        #pragma unroll
        for (int j = 0; j < 4; ++j)
            bfr[j] = *(const short8*)((const char*)lB + bufb + offB[j]);

        if (t < 10) STAGE_P((t + 2) % 3, (t + 2) * 32);

        __builtin_amdgcn_s_setprio(1);
        #pragma unroll
        for (int i = 0; i < 4; ++i)
            #pragma unroll
            for (int j = 0; j < 4; ++j)
                acc[i][j] = __builtin_amdgcn_mfma_f32_16x16x32_bf16(af[i], bfr[j], acc[i][j], 0, 0, 0);
        __builtin_amdgcn_s_setprio(0);
    }
    #undef STAGE_P

    const int r0 = tM + wm + (rg << 2);
    #pragma unroll
    for (int j = 0; j < 4; ++j) {
        const int col = tN + wn + 16 * j + cg;
        const float bv = bias[col];
        #pragma unroll
        for (int i = 0; i < 4; ++i) {
            #pragma unroll
            for (int r = 0; r < 4; ++r) {
                const int row = r0 + 16 * i + r;
                out[(size_t)row * CDIM + col] = acc[i][j][r] + bv;
            }
        }
    }
}

// =====================================================================
extern "C" void kernel_launch(void* const* d_in, const int* in_sizes, int n_in,
                              void* d_out, int out_size, void* d_ws, size_t ws_size,
                              hipStream_t stream) {
    const float* x      = (const float*)d_in[0];
    const float* mask   = (const float*)d_in[1];
    const float* qkv_w  = (const float*)d_in[2];
    const float* qkv_b  = (const float*)d_in[3];
    const float* proj_w = (const float*)d_in[4];
    const float* proj_b = (const float*)d_in[5];
    const float* rpb    = (const float*)d_in[6];
    float* out = (float*)d_out;

    unsigned short* ws_qkv  = (unsigned short*)d_ws;                        // 3*B*H*N*hd
    unsigned short* xbf     = ws_qkv + (size_t)3 * BWIN * HNUM * NTOK * HD; // M*C (aliased)
    unsigned short* ws_attn = xbf;   // x_bf16 dead once qkv_kernel completes
    unsigned short* wqbf    = xbf + (size_t)MTOT * CDIM;                    // 3*C*C
    unsigned short* wpbf    = wqbf + (size_t)3 * CDIM * CDIM;               // C*C
    float* cbias            = (float*)(wpbf + (size_t)CDIM * CDIM);        // 64*12*4096 f32

    convert_kernel<<<XBLK + WQBLK + WPBLK, 256, 0, stream>>>(x, qkv_w, proj_w, xbf, wqbf, wpbf);
    bias_kernel<<<dim3(64, HNUM), 256, 0, stream>>>(mask, rpb, cbias);
    qkv_kernel<<<7056, 256, 0, stream>>>(xbf, wqbf, qkv_b, ws_qkv);
    attn_kernel<<<BWIN, 256, 0, stream>>>(ws_qkv, cbias, ws_attn);
    proj_kernel<<<2352, 256, 0, stream>>>(ws_attn, wpbf, proj_b, out);
}

// Round 9
// 576.013 us; speedup vs baseline: 1.1615x; 1.0216x over previous
//
#include <hip/hip_runtime.h>
#include <stdint.h>
#include <stddef.h>

// ---- problem constants ----
#define BWIN 2048
#define NTOK 49
#define CDIM 384
#define HNUM 12
#define HD   32
#define MTOT (BWIN * NTOK)          // 100352 rows = 784 * 128
#define LOG2E 1.4426950408889634f
// q scale folded with log2(e): logits come out of MFMA in log2 domain
#define QSCALE ((float)(0.17677669529663687 * 1.4426950408889634))

typedef __attribute__((ext_vector_type(8))) short short8;   // 8 bf16 (4 VGPRs)
typedef __attribute__((ext_vector_type(4))) float floatx4;  // MFMA acc

__device__ __forceinline__ unsigned short f2bf(float f) {
    union { float f; unsigned u; } v; v.f = f;
    unsigned u = v.u;
    u = u + 0x7fffu + ((u >> 16) & 1u);   // round-to-nearest-even
    return (unsigned short)(u >> 16);
}

// async global->LDS, 16 B per lane; LDS dest = wave-uniform base + lane*16
__device__ __forceinline__ void gload16(const void* g, void* l) {
    __builtin_amdgcn_global_load_lds(
        (const __attribute__((address_space(1))) void*)g,
        (__attribute__((address_space(3))) void*)l, 16, 0, 0);
}

// =====================================================================
// Kernel 0: fp32 -> bf16 pre-convert (x, qkv_w, proj_w), 2048 elems/block
// =====================================================================
#define XBLK  18816   // 100352*384 / 2048
#define WQBLK 216     // 3*384*384 / 2048
#define WPBLK 72      // 384*384   / 2048
__global__ __launch_bounds__(256) void convert_kernel(
    const float* __restrict__ x, const float* __restrict__ wq,
    const float* __restrict__ wp, unsigned short* __restrict__ xbf,
    unsigned short* __restrict__ wqbf, unsigned short* __restrict__ wpbf)
{
    int bid = blockIdx.x;
    const float* src; unsigned short* dst; size_t base;
    if (bid < XBLK)              { src = x;  dst = xbf;  base = (size_t)bid * 2048; }
    else if (bid < XBLK + WQBLK) { src = wq; dst = wqbf; base = (size_t)(bid - XBLK) * 2048; }
    else                         { src = wp; dst = wpbf; base = (size_t)(bid - XBLK - WQBLK) * 2048; }
    const size_t i = base + (size_t)threadIdx.x * 8;
    float4 a = *(const float4*)(src + i);
    float4 b = *(const float4*)(src + i + 4);
    unsigned short o[8] = {f2bf(a.x), f2bf(a.y), f2bf(a.z), f2bf(a.w),
                           f2bf(b.x), f2bf(b.y), f2bf(b.z), f2bf(b.w)};
    *(uint4*)(dst + i) = *(uint4*)o;
}

// =====================================================================
// Kernel 0b: combined bias table in MFMA accumulator fragment order.
//   cb[bm][h][tid][j*4+r] = (rpb[rel(row,col)] + mask[bm][row][col]) * LOG2E
//   out-of-range slots = -1e30 (exp2 -> 0, so no predicates in attn)
// =====================================================================
__global__ __launch_bounds__(256) void bias_kernel(
    const float* __restrict__ mask, const float* __restrict__ rpb,
    float* __restrict__ cb)
{
    const int bm = blockIdx.x, h = blockIdx.y;
    const int tid = threadIdx.x;
    const int w = tid >> 6, lane = tid & 63;
    const int cg = lane & 15, rg = lane >> 4;
    const int rbase = 16 * w + (rg << 2);
    const float* mk = mask + (size_t)bm * (NTOK * NTOK);
    float o[16];
    #pragma unroll
    for (int j = 0; j < 4; ++j) {
        const int col = 16 * j + cg;
        const bool vc = col < NTOK;
        int yj = 0, xj = 0;
        if (vc) { yj = col / 7; xj = col - yj * 7; }
        #pragma unroll
        for (int r = 0; r < 4; ++r) {
            const int row = rbase + r;
            float v = -1e30f;
            if (vc && row < NTOK) {
                const int yi = row / 7, xi = row - yi * 7;
                const int rel = (yi - yj + 6) * 13 + (xi - xj + 6);
                v = (rpb[rel * HNUM + h] + mk[row * NTOK + col]) * LOG2E;
            }
            o[4 * j + r] = v;
        }
    }
    float* dst = cb + ((size_t)bm * HNUM + h) * 4096 + (size_t)tid * 16;
    #pragma unroll
    for (int j = 0; j < 4; ++j)
        *(float4*)(dst + 4 * j) = *(const float4*)(o + 4 * j);
}

// =====================================================================
// Kernel 1: qkv = xbf @ wqbf^T + qkv_b -> scattered bf16 [3][B][H][N][hd]
// r3 verified-best: XCD-chunked swizzle + LDS XOR swizzle + 3-buffer
// counted-vmcnt pipeline (steady vmcnt(4), raw barriers, setprio).
// FROZEN: 2 nulls + 2 regressions on further K-loop changes.
// =====================================================================
__global__ __launch_bounds__(256) void qkv_kernel(
    const unsigned short* __restrict__ a, const unsigned short* __restrict__ b,
    const float* __restrict__ bias, unsigned short* __restrict__ outq)
{
    __shared__ __align__(16) unsigned short lA[3][128 * 32];
    __shared__ __align__(16) unsigned short lB[3][128 * 32];

    const int tid = threadIdx.x;
    const int lane = tid & 63, w = tid >> 6;

    // XCD-chunked swizzle: 7056 blocks, 7056/8 = 882 per XCD (exact)
    const int bid = blockIdx.x;
    const int wg = (bid & 7) * 882 + (bid >> 3);
    const int tN = (wg % 9) * 128;
    const int tM = (wg / 9) * 128;

    const int X = (lane << 4) ^ (((lane >> 3) & 7) << 4);
    const int srow = (w << 5) + (X >> 6);
    const int scol = (X & 63) >> 1;
    const unsigned short* gA = a + (size_t)(tM + srow) * CDIM + scol;
    const unsigned short* gB = b + (size_t)(tN + srow) * CDIM + scol;

    const int wm = (w & 1) << 6, wn = (w >> 1) << 6;
    const int cg = lane & 15, rg = lane >> 4;

    floatx4 acc[4][4];
    #pragma unroll
    for (int i = 0; i < 4; ++i)
        #pragma unroll
        for (int j = 0; j < 4; ++j) acc[i][j] = (floatx4){0.f, 0.f, 0.f, 0.f};

    int offA[4], offB[4];
    #pragma unroll
    for (int i = 0; i < 4; ++i) {
        const int rowA = wm + 16 * i + cg;
        const int sA = (rowA << 6) + (rg << 4);
        offA[i] = sA ^ (((sA >> 7) & 7) << 4);
        const int rowB = wn + 16 * i + cg;
        const int sB = (rowB << 6) + (rg << 4);
        offB[i] = sB ^ (((sB >> 7) & 7) << 4);
    }

    #define STAGE_Q(BUF, K0) do {                                          \
        unsigned short* _lAb = &lA[(BUF)][w << 10];                        \
        unsigned short* _lBb = &lB[(BUF)][w << 10];                        \
        gload16(gA + (K0),              _lAb);                             \
        gload16(gA + (K0) + 16 * CDIM,  _lAb + 512);                       \
        gload16(gB + (K0),              _lBb);                             \
        gload16(gB + (K0) + 16 * CDIM,  _lBb + 512);                       \
    } while (0)

    STAGE_Q(0, 0);
    STAGE_Q(1, 32);

    #pragma unroll
    for (int t = 0; t < 12; ++t) {
        if (t < 11) asm volatile("s_waitcnt vmcnt(4)" ::: "memory");
        else        asm volatile("s_waitcnt vmcnt(0)" ::: "memory");
        __builtin_amdgcn_s_barrier();
        __builtin_amdgcn_sched_barrier(0);

        const int bufb = (t % 3) * 8192;
        short8 af[4], bfr[4];
        #pragma unroll
        for (int i = 0; i < 4; ++i)
            af[i] = *(const short8*)((const char*)lA + bufb + offA[i]);
        #pragma unroll
        for (int j = 0; j < 4; ++j)
            bfr[j] = *(const short8*)((const char*)lB + bufb + offB[j]);

        if (t < 10) STAGE_Q((t + 2) % 3, (t + 2) * 32);

        __builtin_amdgcn_s_setprio(1);
        #pragma unroll
        for (int i = 0; i < 4; ++i)
            #pragma unroll
            for (int j = 0; j < 4; ++j)
                acc[i][j] = __builtin_amdgcn_mfma_f32_16x16x32_bf16(af[i], bfr[j], acc[i][j], 0, 0, 0);
        __builtin_amdgcn_s_setprio(0);
    }
    #undef STAGE_Q

    const int r0 = tM + wm + (rg << 2);
    float bv[4], sc[4];
    size_t cjo[4];
    #pragma unroll
    for (int j = 0; j < 4; ++j) {
        const int col = tN + wn + 16 * j + cg;
        bv[j] = bias[col];
        const int which = col / CDIM;
        const int rem = col - which * CDIM;
        const int h = rem >> 5, d = rem & 31;
        sc[j] = (which == 0) ? QSCALE : 1.0f;
        cjo[j] = (size_t)which * (BWIN * HNUM * NTOK * HD)
               + (size_t)h * (NTOK * HD) + d;
    }
    #pragma unroll
    for (int i = 0; i < 4; ++i) {
        #pragma unroll
        for (int r = 0; r < 4; ++r) {
            const int row = r0 + 16 * i + r;
            const int bb = row / NTOK;
            const int n = row - bb * NTOK;
            const size_t ro = (size_t)bb * (HNUM * NTOK * HD) + (size_t)n * HD;
            #pragma unroll
            for (int j = 0; j < 4; ++j)
                outq[cjo[j] + ro] = f2bf((acc[i][j][r] + bv[j]) * sc[j]);
        }
    }
}

// =====================================================================
// Kernel 2: MFMA attention — verified 1-(b,h)-per-block structure, with
// XCD-locality decode: blocks on XCD x only touch cb rows {8x..8x+7}
// (per-XCD cb working set 1.5 MB -> L2-resident instead of L3).
//   bid: xcd=bid&7, u=(bid>>3)&7, t2=bid>>6, h=t2%12, v=t2/12,
//   b = u + 8*xcd + 64*v   (bijective on [0,24576))
// =====================================================================
__global__ __launch_bounds__(256) void attn_kernel(
    const unsigned short* __restrict__ qkv, const float* __restrict__ cb,
    unsigned short* __restrict__ outa)
{
    __shared__ __align__(16) unsigned short lq[64][40];
    __shared__ __align__(16) unsigned short lk[64][40];
    __shared__ __align__(16) unsigned short lvt[32][72];
    __shared__ __align__(16) unsigned short lp[64][72];

    const int bid = blockIdx.x;
    const int xcd = bid & 7;
    const int u = (bid >> 3) & 7;
    const int t2 = bid >> 6;
    const int h = t2 % 12;
    const int v = t2 / 12;
    const int b = u + 8 * xcd + 64 * v;

    const int tid = threadIdx.x;
    const size_t WHICH = (size_t)BWIN * HNUM * NTOK * HD;
    const size_t base = ((size_t)b * HNUM + h) * (NTOK * HD);

    // issue cb fragment loads early (independent of LDS staging)
    const float* cbp = cb + ((size_t)(b & 63) * HNUM + h) * 4096 + (size_t)tid * 16;
    floatx4 z[4];
    #pragma unroll
    for (int j = 0; j < 4; ++j) z[j] = *(const floatx4*)(cbp + 4 * j);

    // phase 0: zero pads, stage Q/K into LDS, V into registers
    for (int e = tid; e < 1152; e += 256)
        ((unsigned*)&lvt[0][0])[e] = 0u;
    if (tid < 240) {
        const int r = 49 + (tid >> 4), c = (tid & 15) * 2;
        *(unsigned*)&lq[r][c] = 0u;
        *(unsigned*)&lk[r][c] = 0u;
    }
    uint4 vreg;
    if (tid < 196) {
        const int n = tid >> 2, d = (tid & 3) * 8;
        *(uint4*)&lq[n][d] = *(const uint4*)(qkv + base + tid * 8);
        *(uint4*)&lk[n][d] = *(const uint4*)(qkv + base + WHICH + tid * 8);
        vreg = *(const uint4*)(qkv + base + 2 * WHICH + tid * 8);
    }
    __syncthreads();

    // phase 1: V transpose write (overlaps QK compute of other waves)
    if (tid < 196) {
        const int n = tid >> 2, d0 = (tid & 3) * 8;
        const unsigned short* vp = (const unsigned short*)&vreg;
        #pragma unroll
        for (int jj = 0; jj < 8; ++jj)
            lvt[d0 + jj][n] = vp[jj];
    }

    const int w = tid >> 6, lane = tid & 63;
    const int cg = lane & 15;
    const int rg = lane >> 4;
    const int rbase = 16 * w + rg * 4;

    short8 aq = *(const short8*)&lq[16 * w + cg][rg * 8];
    floatx4 s[4];
    #pragma unroll
    for (int j = 0; j < 4; ++j) {
        short8 bk = *(const short8*)&lk[16 * j + cg][rg * 8];
        s[j] = __builtin_amdgcn_mfma_f32_16x16x32_bf16(aq, bk, z[j], 0, 0, 0);
    }

    // softmax: logits already in log2 domain, pads are -1e30 -> exp2 = 0
    float l[4] = {0.f, 0.f, 0.f, 0.f};
    #pragma unroll
    for (int j = 0; j < 4; ++j) {
        const int col = 16 * j + cg;
        #pragma unroll
        for (int r = 0; r < 4; ++r) {
            const float e = exp2f(s[j][r]);
            l[r] += e;
            lp[rbase + r][col] = f2bf(e);
        }
    }
    #pragma unroll
    for (int st = 1; st < 16; st <<= 1) {
        #pragma unroll
        for (int r = 0; r < 4; ++r) l[r] += __shfl_xor(l[r], st);
    }
    float linv[4];
    #pragma unroll
    for (int r = 0; r < 4; ++r) linv[r] = 1.f / l[r];
    __syncthreads();

    #pragma unroll
    for (int n = 0; n < 2; ++n) {
        floatx4 o = {0, 0, 0, 0};
        #pragma unroll
        for (int kk = 0; kk < 2; ++kk) {
            short8 ap = *(const short8*)&lp[16 * w + cg][kk * 32 + rg * 8];
            short8 bv = *(const short8*)&lvt[16 * n + cg][kk * 32 + rg * 8];
            o = __builtin_amdgcn_mfma_f32_16x16x32_bf16(ap, bv, o, 0, 0, 0);
        }
        #pragma unroll
        for (int r = 0; r < 4; ++r) {
            const int row = rbase + r;
            if (row < NTOK)
                outa[((size_t)b * NTOK + row) * CDIM + h * HD + n * 16 + cg] =
                    f2bf(o[r] * linv[r]);
        }
    }
}

// =====================================================================
// Kernel 3: out = a @ wpbf^T + proj_b; r3 counted-vmcnt pipeline
// =====================================================================
__global__ __launch_bounds__(256) void proj_kernel(
    const unsigned short* __restrict__ a, const unsigned short* __restrict__ b,
    const float* __restrict__ bias, float* __restrict__ out)
{
    __shared__ __align__(16) unsigned short lA[3][128 * 32];
    __shared__ __align__(16) unsigned short lB[3][128 * 32];

    const int tid = threadIdx.x;
    const int lane = tid & 63, w = tid >> 6;

    const int bid = blockIdx.x;
    const int wg = (bid & 7) * 294 + (bid >> 3);
    const int tN = (wg % 3) * 128;
    const int tM = (wg / 3) * 128;

    const int X = (lane << 4) ^ (((lane >> 3) & 7) << 4);
    const int srow = (w << 5) + (X >> 6);
    const int scol = (X & 63) >> 1;
    const unsigned short* gA = a + (size_t)(tM + srow) * CDIM + scol;
    const unsigned short* gB = b + (size_t)(tN + srow) * CDIM + scol;

    const int wm = (w & 1) << 6, wn = (w >> 1) << 6;
    const int cg = lane & 15, rg = lane >> 4;

    floatx4 acc[4][4];
    #pragma unroll
    for (int i = 0; i < 4; ++i)
        #pragma unroll
        for (int j = 0; j < 4; ++j) acc[i][j] = (floatx4){0.f, 0.f, 0.f, 0.f};

    int offA[4], offB[4];
    #pragma unroll
    for (int i = 0; i < 4; ++i) {
        const int rowA = wm + 16 * i + cg;
        const int sA = (rowA << 6) + (rg << 4);
        offA[i] = sA ^ (((sA >> 7) & 7) << 4);
        const int rowB = wn + 16 * i + cg;
        const int sB = (rowB << 6) + (rg << 4);
        offB[i] = sB ^ (((sB >> 7) & 7) << 4);
    }

    #define STAGE_P(BUF, K0) do {                                          \
        unsigned short* _lAb = &lA[(BUF)][w << 10];                        \
        unsigned short* _lBb = &lB[(BUF)][w << 10];                        \
        gload16(gA + (K0),              _lAb);                             \
        gload16(gA + (K0) + 16 * CDIM,  _lAb + 512);                       \
        gload16(gB + (K0),              _lBb);                             \
        gload16(gB + (K0) + 16 * CDIM,  _lBb + 512);                       \
    } while (0)

    STAGE_P(0, 0);
    STAGE_P(1, 32);

    #pragma unroll
    for (int t = 0; t < 12; ++t) {
        if (t < 11) asm volatile("s_waitcnt vmcnt(4)" ::: "memory");
        else        asm volatile("s_waitcnt vmcnt(0)" ::: "memory");
        __builtin_amdgcn_s_barrier();
        __builtin_amdgcn_sched_barrier(0);

        const int bufb = (t % 3) * 8192;
        short8 af[4], bfr[4];
        #pragma unroll
        for (int i = 0; i < 4; ++i)
            af[i] = *(const short8*)((const char*)lA + bufb + offA[i]);
        #pragma unroll
        for (int j = 0; j < 4; ++j)
            bfr[j] = *(const short8*)((const char*)lB + bufb + offB[j]);

        if (t < 10) STAGE_P((t + 2) % 3, (t + 2) * 32);

        __builtin_amdgcn_s_setprio(1);
        #pragma unroll
        for (int i = 0; i < 4; ++i)
            #pragma unroll
            for (int j = 0; j < 4; ++j)
                acc[i][j] = __builtin_amdgcn_mfma_f32_16x16x32_bf16(af[i], bfr[j], acc[i][j], 0, 0, 0);
        __builtin_amdgcn_s_setprio(0);
    }
    #undef STAGE_P

    const int r0 = tM + wm + (rg << 2);
    #pragma unroll
    for (int j = 0; j < 4; ++j) {
        const int col = tN + wn + 16 * j + cg;
        const float bv = bias[col];
        #pragma unroll
        for (int i = 0; i < 4; ++i) {
            #pragma unroll
            for (int r = 0; r < 4; ++r) {
                const int row = r0 + 16 * i + r;
                out[(size_t)row * CDIM + col] = acc[i][j][r] + bv;
            }
        }
    }
}

// =====================================================================
extern "C" void kernel_launch(void* const* d_in, const int* in_sizes, int n_in,
                              void* d_out, int out_size, void* d_ws, size_t ws_size,
                              hipStream_t stream) {
    const float* x      = (const float*)d_in[0];
    const float* mask   = (const float*)d_in[1];
    const float* qkv_w  = (const float*)d_in[2];
    const float* qkv_b  = (const float*)d_in[3];
    const float* proj_w = (const float*)d_in[4];
    const float* proj_b = (const float*)d_in[5];
    const float* rpb    = (const float*)d_in[6];
    float* out = (float*)d_out;

    unsigned short* ws_qkv  = (unsigned short*)d_ws;                        // 3*B*H*N*hd
    unsigned short* xbf     = ws_qkv + (size_t)3 * BWIN * HNUM * NTOK * HD; // M*C (aliased)
    unsigned short* ws_attn = xbf;   // x_bf16 dead once qkv_kernel completes
    unsigned short* wqbf    = xbf + (size_t)MTOT * CDIM;                    // 3*C*C
    unsigned short* wpbf    = wqbf + (size_t)3 * CDIM * CDIM;               // C*C
    float* cbias            = (float*)(wpbf + (size_t)CDIM * CDIM);        // 64*12*4096 f32

    convert_kernel<<<XBLK + WQBLK + WPBLK, 256, 0, stream>>>(x, qkv_w, proj_w, xbf, wqbf, wpbf);
    bias_kernel<<<dim3(64, HNUM), 256, 0, stream>>>(mask, rpb, cbias);
    qkv_kernel<<<7056, 256, 0, stream>>>(xbf, wqbf, qkv_b, ws_qkv);
    attn_kernel<<<24576, 256, 0, stream>>>(ws_qkv, cbias, ws_attn);
    proj_kernel<<<2352, 256, 0, stream>>>(ws_attn, wpbf, proj_b, out);
}